// Round 13
// baseline (85.873 us; speedup 1.0000x reference)
//
#include <hip/hip_runtime.h>
#include <float.h>

#define NSEG 8
#define SEGLEN 1024   // B*Ls*H*D = 1*4*8*32
#define BIGV 1e30f    // "infinity" for invalid DP cells
#define PADV 1e18f    // x-pad sentinel: huge cost, no overflow over a chunk

#define NW 4          // waves per block (256 threads); wave owns 256 cols
#define CH 64         // steps per chunk (one flag handshake per chunk)
#define NCH 17        // local steps 0..1087 (lane 63 hits row 1023 at t=1086)
#define XLEN 1152     // xl[t] = x[t] for t<1024, else PADV (read up to 1087)
#define BSTRIDE 1160  // bnd[w][r+64] = D[r, 256w-1]; max read index 1152

#define DPPF(OLD, SRC, CTRL, RM, BM, BC)                                      \
    __int_as_float(__builtin_amdgcn_update_dpp(                               \
        __float_as_int(OLD), __float_as_int(SRC), CTRL, RM, BM, BC))
// lane i <- lane i-1; lane 0 <- OLD[lane 0]   (validated R2-R12)
#define WSHIFT1(OLD, SRC) DPPF(OLD, SRC, 0x138, 0xF, 0xF, false)
// stream advance: lane i <- lane i+1 (validated R7: step-s value sits at
// lane 0 after s advances; only lane 0 of the stream is ever consumed)
#define WSTREAM(SRC) DPPF(SRC, SRC, 0x130, 0xF, 0xF, false)

// Lane-skewed systolic DTW, 4 waves (1 per SIMD). Wave w owns cols
// [256w,256w+256); lane L owns c_e = 256w+4L+e, e in 0..3.
// At local step t, lane L computes ROW r = t - L of its four columns.
// R13: (1) zero SGPR traffic in the hot loop -- x and boundary values
// travel in DPP stream registers (xstr/bstr), injected via the WSHIFT1
// old-operand; (2) the 4 cells use the min-plus scan identity
//   d[e] = ls[e] + cummin(min(a0,lf), a1-ls0, a2-ls1, a3-ls2)[e]
// (a_e = min(P_e, P_{e-1}), diag seed dgl for e=0) which shortens the
// lf-dependent serial chain from 9 ops (d-form left-to-right) to 6, making
// the step issue-bound at 1 wave/SIMD. Mathematically identical to the
// min3 recurrence (min is exact; adds reassociate within fp tolerance --
// the reference itself uses this scan form across whole rows).
// Rows r<0 / r>1023 compute garbage >= ~1e18 (PADV costs) acting as +inf;
// scan-form intermediates may go negative-huge but sums stay >= ~1e18.
// Cross-wave boundary: lane 63 writes D[r,256w+255] to bnd[w+1][r+64] each
// step (others hit a dump sink, branchless); monotone chunk-counter
// handshake with lag 2 (consumer chunk tc reads rows <= 64tc+64).
__global__ __launch_bounds__(256) void dtw_sk4_kernel(const float* __restrict__ q,
                                                      const float* __restrict__ kk,
                                                      float* __restrict__ dists) {
    __shared__ float xl[XLEN];
    __shared__ float bnd[NW + 1][BSTRIDE];  // bnd[0] = BIGV region for wave 0
    __shared__ float dump[128];             // sink, indices up to 125 (R8 lesson)
    __shared__ int flagsA[NW + 1];          // [0]=sentinel; [w+1]=wave w chunks done
    const int tid = threadIdx.x;
    const int lane = tid & 63;
    const int wv = tid >> 6;
    const int pair = blockIdx.x;            // 0..63
    const float* __restrict__ x = q + (pair >> 3) * SEGLEN;
    const float* __restrict__ y = kk + (pair & 7) * SEGLEN;

    for (int t = tid; t < XLEN; t += 256) xl[t] = (t < SEGLEN) ? x[t] : PADV;
    // flat index 63 = bnd[0][63] = virtual corner D[-1,-1] = 0; rest BIGV.
    for (int t = tid; t < (NW + 1) * BSTRIDE; t += 256)
        (&bnd[0][0])[t] = (t == 63) ? 0.f : BIGV;
    if (tid < NW + 1) flagsA[tid] = (tid == 0) ? 0x7FFFFFFF : 0;

    const float4 y4 = *(const float4*)(y + wv * 256 + lane * 4);
    const float yv0 = y4.x, yv1 = y4.y, yv2 = y4.z, yv3 = y4.w;

    __syncthreads();   // the only block-wide barrier

    const float* __restrict__ br = &bnd[wv][0];   // left neighbor's boundary

    // wait for the first 2 producer chunks before reading init boundary
    {
        const int need0 = (NCH < 2) ? NCH : 2;
        while (__hip_atomic_load(&flagsA[wv], __ATOMIC_ACQUIRE,
                                 __HIP_MEMORY_SCOPE_WORKGROUP) < need0)
            __builtin_amdgcn_s_sleep(1);
    }
    float P0 = BIGV, P1 = BIGV, P2 = BIGV, P3 = BIGV, xreg = PADV;
    float lf = br[64];    // D[0, 256w-1] (wave 0: BIGV); real only for lane 0
    float dgl = br[63];   // D[-1,256w-1] (wave 0: corner 0)

// One systolic step. Cells use OLD lf/dgl; n1 preps next step's lf.
#define STEP(s) {                                                             \
    xreg = WSHIFT1(xstr, xreg);                                               \
    xstr = WSTREAM(xstr);                                                     \
    const float ls0 = fabsf(xreg - yv0);                                      \
    const float ls1 = ls0 + fabsf(xreg - yv1);                                \
    const float ls2 = ls1 + fabsf(xreg - yv2);                                \
    const float ls3 = ls2 + fabsf(xreg - yv3);                                \
    const float a0 = fminf(P0, dgl);                                          \
    const float a1 = fminf(P1, P0);                                           \
    const float a2 = fminf(P2, P1);                                           \
    const float a3 = fminf(P3, P2);                                           \
    const float r0 = fminf(a0, lf);                                           \
    const float r1 = fminf(r0, a1 - ls0);                                     \
    const float r2 = fminf(r1, a2 - ls1);                                     \
    const float r3 = fminf(r2, a3 - ls2);                                     \
    P0 = ls0 + r0; P1 = ls1 + r1; P2 = ls2 + r2; P3 = ls3 + r3;               \
    const float n1 = WSHIFT1(bstr, P3);                                       \
    bstr = WSTREAM(bstr);                                                     \
    dgl = lf; lf = n1;                                                        \
    va[(s)] = P3;                                                             \
}
#define STEP8(s) STEP(s) STEP((s)+1) STEP((s)+2) STEP((s)+3)                  \
                 STEP((s)+4) STEP((s)+5) STEP((s)+6) STEP((s)+7)

#pragma unroll 1
    for (int tc = 0; tc < NCH; ++tc) {
        // consumer chunk tc reads bnd rows <= 64tc+64 (index 64tc+128);
        // producer writes row r at its step r+63 -> needs chunk tc+1 done
        // (flag >= tc+2), capped at NCH (later indices are BIGV pad).
        const int need = (tc + 2 < NCH) ? (tc + 2) : NCH;
        while (__hip_atomic_load(&flagsA[wv], __ATOMIC_ACQUIRE,
                                 __HIP_MEMORY_SCOPE_WORKGROUP) < need)
            __builtin_amdgcn_s_sleep(1);

        // stream registers: value for step s sits at lane s; consumed at
        // lane 0 via the WSHIFT1 old-operand, advanced by WSTREAM.
        float xstr = xl[CH * tc + lane];          // x[64tc+s]
        float bstr = br[CH * tc + 65 + lane];     // bnd row 64tc+s+1
        // boundary write: lane 63 -> bnd[wv+1][64tc+1+s]; others -> dump
        float* va = (lane == 63) ? &bnd[wv + 1][CH * tc + 1] : &dump[lane];

        STEP8(0) STEP8(8) STEP8(16) STEP8(24) STEP8(32) STEP8(40) STEP8(48) STEP8(56)

        // publish chunk tc (release orders the ds_writes above before the flag)
        __hip_atomic_store(&flagsA[wv + 1], tc + 1, __ATOMIC_RELEASE,
                           __HIP_MEMORY_SCOPE_WORKGROUP);
    }
#undef STEP
#undef STEP8

    // D[1023,1023]: wave 3 lane 63 col e=3 at t=1086 -> bnd[NW][1087]
    // (t=1087 overwrites P3 with a garbage row, so read back from LDS).
    if (wv == NW - 1 && lane == 0) dists[pair] = bnd[NW][1087];
}

// out[i*1024+p] = sum_j softmax_j(0.5*dists[i,:])[j] * values[j*1024+p]
__global__ __launch_bounds__(256) void softmax_out_kernel(const float* __restrict__ v,
                                                          const float* __restrict__ dists,
                                                          float* __restrict__ out) {
    const int o = blockIdx.x * blockDim.x + threadIdx.x;
    if (o >= NSEG * SEGLEN) return;
    const int i = o >> 10;
    const int p = o & 1023;

    float l[NSEG];
    float mx = -FLT_MAX;
#pragma unroll
    for (int j = 0; j < NSEG; ++j) {
        l[j] = 0.5f * dists[i * NSEG + j];
        mx = fmaxf(mx, l[j]);
    }
    float s = 0.f;
#pragma unroll
    for (int j = 0; j < NSEG; ++j) {
        l[j] = expf(l[j] - mx);
        s += l[j];
    }
    const float inv = 1.f / s;
    float acc = 0.f;
#pragma unroll
    for (int j = 0; j < NSEG; ++j) acc += (l[j] * inv) * v[j * SEGLEN + p];
    out[o] = acc;
}

extern "C" void kernel_launch(void* const* d_in, const int* in_sizes, int n_in,
                              void* d_out, int out_size, void* d_ws, size_t ws_size,
                              hipStream_t stream) {
    const float* q = (const float*)d_in[0];   // queries [1,32,8,32] f32
    const float* k = (const float*)d_in[1];   // keys
    const float* v = (const float*)d_in[2];   // values
    float* out = (float*)d_out;               // [8192] f32
    float* dists = (float*)d_ws;              // 64 floats scratch

    dtw_sk4_kernel<<<dim3(NSEG * NSEG), dim3(256), 0, stream>>>(q, k, dists);
    softmax_out_kernel<<<dim3((NSEG * SEGLEN + 255) / 256), dim3(256), 0, stream>>>(v, dists, out);
}

// Round 14
// 72.285 us; speedup vs baseline: 1.1880x; 1.1880x over previous
//
#include <hip/hip_runtime.h>
#include <float.h>

#define NSEG 8
#define SEGLEN 1024   // B*Ls*H*D = 1*4*8*32
#define BIGV 1e30f    // "infinity" for invalid DP cells
#define PADV 1e18f    // x-pad sentinel: huge cost, no overflow over a chunk

#define NW 4          // waves per block (256 threads); wave owns 256 cols
#define CH 64         // steps per chunk (one flag handshake per chunk)
#define NCH 17        // local steps 0..1087 (lane 63 hits row 1023 at t=1086)
#define XLEN 1152     // xl[t] = x[t] for t<1024, else PADV (read up to 1087)
#define BSTRIDE 1160  // bnd[w][r+64] = D[r, 256w-1]; max read index 1152

#define DPPF(OLD, SRC, CTRL, RM, BM, BC)                                      \
    __int_as_float(__builtin_amdgcn_update_dpp(                               \
        __float_as_int(OLD), __float_as_int(SRC), CTRL, RM, BM, BC))
// lane i <- lane i-1; lane 0 <- OLD[lane 0]   (validated R2-R13)
#define WSHIFT1(OLD, SRC) DPPF(OLD, SRC, 0x138, 0xF, 0xF, false)

__device__ __forceinline__ float readlaneF(float v, int l) {
    return __int_as_float(__builtin_amdgcn_readlane(__float_as_int(v), l));
}

// Guaranteed single-instruction 3-input min (chain-critical; clang does not
// reliably fuse fminf(fminf(a,b),c) into v_min3_f32 -- R12's 52 cyc/step
// stall matches the unfused 12-op chain).
__device__ __forceinline__ float min3f(float a, float b, float c) {
    float d;
    asm("v_min3_f32 %0, %1, %2, %3" : "=v"(d) : "v"(a), "v"(b), "v"(c));
    return d;
}

// Lane-skewed systolic DTW, 4 waves (1 per SIMD). Wave w owns cols
// [256w,256w+256); lane L owns c_e = 256w+4L+e, e in 0..3.
// At local step t, lane L computes ROW r = t - L of its four columns:
//   c0 = |x[r]-y0| + min3(P0(up), lf(left: lane L-1 col3 row r), dgl(diag))
//   c1 = |x[r]-y1| + min3(P1, c0, P0)   (left/diag within lane, same step)
//   c2 = |x[r]-y2| + min3(P2, c1, P1)
//   c3 = |x[r]-y3| + min3(P3, c2, P2)
// Lane L-1 runs one row ahead; lf/dgl arrive via ONE end-of-step wf_sr1 of
// c3. x travels the same way: xreg = shift(xreg) with x[t] injected at lane
// 0 from a per-chunk register (per-step ds_read regressed in R11; pure-DPP
// streams regressed in R7/R13 -- readlane inject is the measured optimum).
// Rows r<0 / r>1023 compute garbage >= 1e18 (PADV costs) acting as +inf.
// Cross-wave boundary: lane 63 writes D[r,256w+255] to bnd[w+1][r+64] each
// step (others hit a dump sink, branchless); monotone chunk-counter
// handshake with lag 2 (consumer chunk tc reads rows <= 64tc+64).
__global__ __launch_bounds__(256) void dtw_sk4_kernel(const float* __restrict__ q,
                                                      const float* __restrict__ kk,
                                                      float* __restrict__ dists) {
    __shared__ float xl[XLEN];
    __shared__ float bnd[NW + 1][BSTRIDE];  // bnd[0] = BIGV region for wave 0
    __shared__ float dump[128];             // sink, indices up to 125 (R8 lesson)
    __shared__ int flagsA[NW + 1];          // [0]=sentinel; [w+1]=wave w chunks done
    const int tid = threadIdx.x;
    const int lane = tid & 63;
    const int wv = tid >> 6;
    const int pair = blockIdx.x;            // 0..63
    const float* __restrict__ x = q + (pair >> 3) * SEGLEN;
    const float* __restrict__ y = kk + (pair & 7) * SEGLEN;

    for (int t = tid; t < XLEN; t += 256) xl[t] = (t < SEGLEN) ? x[t] : PADV;
    // flat index 63 = bnd[0][63] = virtual corner D[-1,-1] = 0; rest BIGV.
    for (int t = tid; t < (NW + 1) * BSTRIDE; t += 256)
        (&bnd[0][0])[t] = (t == 63) ? 0.f : BIGV;
    if (tid < NW + 1) flagsA[tid] = (tid == 0) ? 0x7FFFFFFF : 0;

    const float4 y4 = *(const float4*)(y + wv * 256 + lane * 4);
    const float yv0 = y4.x, yv1 = y4.y, yv2 = y4.z, yv3 = y4.w;

    __syncthreads();   // the only block-wide barrier

    const float* __restrict__ br = &bnd[wv][0];   // left neighbor's boundary

    // wait for the first 2 producer chunks before reading init boundary
    {
        const int need0 = (NCH < 2) ? NCH : 2;
        while (__hip_atomic_load(&flagsA[wv], __ATOMIC_ACQUIRE,
                                 __HIP_MEMORY_SCOPE_WORKGROUP) < need0)
            __builtin_amdgcn_s_sleep(1);
    }
    float P0 = BIGV, P1 = BIGV, P2 = BIGV, P3 = BIGV, xreg = PADV;
    float lf = br[64];    // D[0, 256w-1] (wave 0: BIGV); real only for lane 0
    float dgl = br[63];   // D[-1,256w-1] (wave 0: corner 0)

// One systolic step (s compile-time). Cells use OLD lf/dgl; n1 preps next lf.
#define STEP(s) {                                                             \
    xreg = WSHIFT1(readlaneF(xv, (s)), xreg);                                 \
    const float c0n = fabsf(xreg - yv0) + min3f(P0, lf, dgl);                 \
    const float c1n = fabsf(xreg - yv1) + min3f(P1, c0n, P0);                 \
    const float c2n = fabsf(xreg - yv2) + min3f(P2, c1n, P1);                 \
    const float c3n = fabsf(xreg - yv3) + min3f(P3, c2n, P2);                 \
    const float n1 = WSHIFT1(readlaneF(bvv, (s)), c3n);                       \
    dgl = lf; lf = n1; P0 = c0n; P1 = c1n; P2 = c2n; P3 = c3n;                \
    va[(s)] = c3n;                                                            \
}
#define STEP8(s) STEP(s) STEP((s)+1) STEP((s)+2) STEP((s)+3)                  \
                 STEP((s)+4) STEP((s)+5) STEP((s)+6) STEP((s)+7)

#pragma unroll 1
    for (int tc = 0; tc < NCH; ++tc) {
        // consumer chunk tc reads bnd rows <= 64tc+64 (index 64tc+128);
        // producer writes row r at its step r+63 -> needs chunk tc+1 done
        // (flag >= tc+2), capped at NCH (later indices are BIGV pad).
        const int need = (tc + 2 < NCH) ? (tc + 2) : NCH;
        while (__hip_atomic_load(&flagsA[wv], __ATOMIC_ACQUIRE,
                                 __HIP_MEMORY_SCOPE_WORKGROUP) < need)
            __builtin_amdgcn_s_sleep(1);

        const float xv = xl[CH * tc + lane];         // x[64tc+s] inject stream
        const float bvv = br[CH * tc + 65 + lane];   // inject: bnd row 64tc+s+1
        // boundary write: lane 63 -> bnd[wv+1][64tc+1+s]; others -> dump
        float* va = (lane == 63) ? &bnd[wv + 1][CH * tc + 1] : &dump[lane];

        STEP8(0) STEP8(8) STEP8(16) STEP8(24) STEP8(32) STEP8(40) STEP8(48) STEP8(56)

        // publish chunk tc (release orders the ds_writes above before the flag)
        __hip_atomic_store(&flagsA[wv + 1], tc + 1, __ATOMIC_RELEASE,
                           __HIP_MEMORY_SCOPE_WORKGROUP);
    }
#undef STEP
#undef STEP8

    // D[1023,1023]: wave 3 lane 63 col e=3 at t=1086 -> bnd[NW][1087]
    // (t=1087 overwrites P3 with a garbage row, so read back from LDS).
    if (wv == NW - 1 && lane == 0) dists[pair] = bnd[NW][1087];
}

// out[i*1024+p] = sum_j softmax_j(0.5*dists[i,:])[j] * values[j*1024+p]
__global__ __launch_bounds__(256) void softmax_out_kernel(const float* __restrict__ v,
                                                          const float* __restrict__ dists,
                                                          float* __restrict__ out) {
    const int o = blockIdx.x * blockDim.x + threadIdx.x;
    if (o >= NSEG * SEGLEN) return;
    const int i = o >> 10;
    const int p = o & 1023;

    float l[NSEG];
    float mx = -FLT_MAX;
#pragma unroll
    for (int j = 0; j < NSEG; ++j) {
        l[j] = 0.5f * dists[i * NSEG + j];
        mx = fmaxf(mx, l[j]);
    }
    float s = 0.f;
#pragma unroll
    for (int j = 0; j < NSEG; ++j) {
        l[j] = expf(l[j] - mx);
        s += l[j];
    }
    const float inv = 1.f / s;
    float acc = 0.f;
#pragma unroll
    for (int j = 0; j < NSEG; ++j) acc += (l[j] * inv) * v[j * SEGLEN + p];
    out[o] = acc;
}

extern "C" void kernel_launch(void* const* d_in, const int* in_sizes, int n_in,
                              void* d_out, int out_size, void* d_ws, size_t ws_size,
                              hipStream_t stream) {
    const float* q = (const float*)d_in[0];   // queries [1,32,8,32] f32
    const float* k = (const float*)d_in[1];   // keys
    const float* v = (const float*)d_in[2];   // values
    float* out = (float*)d_out;               // [8192] f32
    float* dists = (float*)d_ws;              // 64 floats scratch

    dtw_sk4_kernel<<<dim3(NSEG * NSEG), dim3(256), 0, stream>>>(q, k, dists);
    softmax_out_kernel<<<dim3((NSEG * SEGLEN + 255) / 256), dim3(256), 0, stream>>>(v, dists, out);
}

// Round 15
// 63.831 us; speedup vs baseline: 1.3453x; 1.1324x over previous
//
#include <hip/hip_runtime.h>
#include <float.h>

#define NSEG 8
#define SEGLEN 1024   // B*Ls*H*D = 1*4*8*32
#define BIGV 1e30f    // "infinity" for invalid DP cells
#define PADV 1e18f    // x-pad sentinel: huge cost, no overflow over a chunk

#define NW 4          // waves per block (256 threads); wave owns 256 cols
#define CH 64         // steps per chunk (one flag handshake per chunk)
#define NCH 17        // local steps 0..1087 (lane 63 hits row 1023 at t=1086)
#define XLEN 1152     // xl[t] = x[t] for t<1024, else PADV (read up to 1087)
#define BSTRIDE 1160  // bnd[w][r+64] = D[r, 256w-1]; max read index 1152

#define DPPF(OLD, SRC, CTRL, RM, BM, BC)                                      \
    __int_as_float(__builtin_amdgcn_update_dpp(                               \
        __float_as_int(OLD), __float_as_int(SRC), CTRL, RM, BM, BC))
// lane i <- lane i-1; lane 0 <- OLD[lane 0]   (validated R2-R14)
#define WSHIFT1(OLD, SRC) DPPF(OLD, SRC, 0x138, 0xF, 0xF, false)

__device__ __forceinline__ float readlaneF(float v, int l) {
    return __int_as_float(__builtin_amdgcn_readlane(__float_as_int(v), l));
}

// Lane-skewed systolic DTW, 4 waves (1 per SIMD). Wave w owns cols
// [256w,256w+256); lane L owns c_e = 256w+4L+e, e in 0..3.
// At local step t, lane L computes ROW r = t - L of its four columns:
//   c0 = |x[r]-y0| + min3(P0(up), lf(left: lane L-1 col3 row r), dgl(diag))
//   c1 = |x[r]-y1| + min3(P1, c0, P0)   (left/diag within lane, same step)
//   c2 = |x[r]-y2| + min3(P2, c1, P1)
//   c3 = |x[r]-y3| + min3(P3, c2, P2)
// Lane L-1 runs one row ahead; lf/dgl arrive via ONE end-of-step wf_sr1 of
// c3. x travels the same way (lane-0 inject + wf_sr1).
// R15: inject values for each 8-step group are read (v_readlane) into
// temporaries at the GROUP TOP -- the VALU->SGPR->VALU hazard wait-states
// and s->v movs amortize over 8 steps with scheduling distance, leaving
// ~1 v_mov_b32_dpp per inject on the step itself. (R14's min3 inline asm
// regressed 62->68us -- compiler handles the fmin fusion; reverted.)
// Rows r<0 / r>1023 compute garbage >= 1e18 (PADV costs) acting as +inf.
// Cross-wave boundary: lane 63 writes D[r,256w+255] to bnd[w+1][r+64] each
// step (others hit a dump sink, branchless); monotone chunk-counter
// handshake with lag 2 (consumer chunk tc reads rows <= 64tc+64).
__global__ __launch_bounds__(256) void dtw_sk4_kernel(const float* __restrict__ q,
                                                      const float* __restrict__ kk,
                                                      float* __restrict__ dists) {
    __shared__ float xl[XLEN];
    __shared__ float bnd[NW + 1][BSTRIDE];  // bnd[0] = BIGV region for wave 0
    __shared__ float dump[128];             // sink, indices up to 125 (R8 lesson)
    __shared__ int flagsA[NW + 1];          // [0]=sentinel; [w+1]=wave w chunks done
    const int tid = threadIdx.x;
    const int lane = tid & 63;
    const int wv = tid >> 6;
    const int pair = blockIdx.x;            // 0..63
    const float* __restrict__ x = q + (pair >> 3) * SEGLEN;
    const float* __restrict__ y = kk + (pair & 7) * SEGLEN;

    for (int t = tid; t < XLEN; t += 256) xl[t] = (t < SEGLEN) ? x[t] : PADV;
    // flat index 63 = bnd[0][63] = virtual corner D[-1,-1] = 0; rest BIGV.
    for (int t = tid; t < (NW + 1) * BSTRIDE; t += 256)
        (&bnd[0][0])[t] = (t == 63) ? 0.f : BIGV;
    if (tid < NW + 1) flagsA[tid] = (tid == 0) ? 0x7FFFFFFF : 0;

    const float4 y4 = *(const float4*)(y + wv * 256 + lane * 4);
    const float yv0 = y4.x, yv1 = y4.y, yv2 = y4.z, yv3 = y4.w;

    __syncthreads();   // the only block-wide barrier

    const float* __restrict__ br = &bnd[wv][0];   // left neighbor's boundary

    // wait for the first 2 producer chunks before reading init boundary
    {
        const int need0 = (NCH < 2) ? NCH : 2;
        while (__hip_atomic_load(&flagsA[wv], __ATOMIC_ACQUIRE,
                                 __HIP_MEMORY_SCOPE_WORKGROUP) < need0)
            __builtin_amdgcn_s_sleep(1);
    }
    float P0 = BIGV, P1 = BIGV, P2 = BIGV, P3 = BIGV, xreg = PADV;
    float lf = br[64];    // D[0, 256w-1] (wave 0: BIGV); real only for lane 0
    float dgl = br[63];   // D[-1,256w-1] (wave 0: corner 0)

// One systolic step with pre-hoisted inject values xp (x) and bp (boundary).
#define STEP(s, xp, bp) {                                                     \
    xreg = WSHIFT1(xp, xreg);                                                 \
    const float c0n = fabsf(xreg - yv0) + fminf(fminf(P0, lf), dgl);          \
    const float c1n = fabsf(xreg - yv1) + fminf(fminf(P1, c0n), P0);          \
    const float c2n = fabsf(xreg - yv2) + fminf(fminf(P2, c1n), P1);          \
    const float c3n = fabsf(xreg - yv3) + fminf(fminf(P3, c2n), P2);          \
    const float n1 = WSHIFT1(bp, c3n);                                        \
    dgl = lf; lf = n1; P0 = c0n; P1 = c1n; P2 = c2n; P3 = c3n;                \
    va[(s)] = c3n;                                                            \
}
// 8-step group: hoist all 16 readlanes to the top so the SGPR hazards and
// s->v movs amortize and schedule away from the dependent DPPs.
#define STEP8(s) {                                                            \
    const float xp0 = readlaneF(xv, (s)+0), xp1 = readlaneF(xv, (s)+1);       \
    const float xp2 = readlaneF(xv, (s)+2), xp3 = readlaneF(xv, (s)+3);       \
    const float xp4 = readlaneF(xv, (s)+4), xp5 = readlaneF(xv, (s)+5);       \
    const float xp6 = readlaneF(xv, (s)+6), xp7 = readlaneF(xv, (s)+7);       \
    const float bp0 = readlaneF(bvv, (s)+0), bp1 = readlaneF(bvv, (s)+1);     \
    const float bp2 = readlaneF(bvv, (s)+2), bp3 = readlaneF(bvv, (s)+3);     \
    const float bp4 = readlaneF(bvv, (s)+4), bp5 = readlaneF(bvv, (s)+5);     \
    const float bp6 = readlaneF(bvv, (s)+6), bp7 = readlaneF(bvv, (s)+7);     \
    STEP((s)+0, xp0, bp0) STEP((s)+1, xp1, bp1)                               \
    STEP((s)+2, xp2, bp2) STEP((s)+3, xp3, bp3)                               \
    STEP((s)+4, xp4, bp4) STEP((s)+5, xp5, bp5)                               \
    STEP((s)+6, xp6, bp6) STEP((s)+7, xp7, bp7)                               \
}

#pragma unroll 1
    for (int tc = 0; tc < NCH; ++tc) {
        // consumer chunk tc reads bnd rows <= 64tc+64 (index 64tc+128);
        // producer writes row r at its step r+63 -> needs chunk tc+1 done
        // (flag >= tc+2), capped at NCH (later indices are BIGV pad).
        const int need = (tc + 2 < NCH) ? (tc + 2) : NCH;
        while (__hip_atomic_load(&flagsA[wv], __ATOMIC_ACQUIRE,
                                 __HIP_MEMORY_SCOPE_WORKGROUP) < need)
            __builtin_amdgcn_s_sleep(1);

        const float xv = xl[CH * tc + lane];         // x[64tc+s] inject stream
        const float bvv = br[CH * tc + 65 + lane];   // inject: bnd row 64tc+s+1
        // boundary write: lane 63 -> bnd[wv+1][64tc+1+s]; others -> dump
        float* va = (lane == 63) ? &bnd[wv + 1][CH * tc + 1] : &dump[lane];

        STEP8(0) STEP8(8) STEP8(16) STEP8(24) STEP8(32) STEP8(40) STEP8(48) STEP8(56)

        // publish chunk tc (release orders the ds_writes above before the flag)
        __hip_atomic_store(&flagsA[wv + 1], tc + 1, __ATOMIC_RELEASE,
                           __HIP_MEMORY_SCOPE_WORKGROUP);
    }
#undef STEP
#undef STEP8

    // D[1023,1023]: wave 3 lane 63 col e=3 at t=1086 -> bnd[NW][1087]
    // (t=1087 overwrites P3 with a garbage row, so read back from LDS).
    if (wv == NW - 1 && lane == 0) dists[pair] = bnd[NW][1087];
}

// out[i*1024+p] = sum_j softmax_j(0.5*dists[i,:])[j] * values[j*1024+p]
__global__ __launch_bounds__(256) void softmax_out_kernel(const float* __restrict__ v,
                                                          const float* __restrict__ dists,
                                                          float* __restrict__ out) {
    const int o = blockIdx.x * blockDim.x + threadIdx.x;
    if (o >= NSEG * SEGLEN) return;
    const int i = o >> 10;
    const int p = o & 1023;

    float l[NSEG];
    float mx = -FLT_MAX;
#pragma unroll
    for (int j = 0; j < NSEG; ++j) {
        l[j] = 0.5f * dists[i * NSEG + j];
        mx = fmaxf(mx, l[j]);
    }
    float s = 0.f;
#pragma unroll
    for (int j = 0; j < NSEG; ++j) {
        l[j] = expf(l[j] - mx);
        s += l[j];
    }
    const float inv = 1.f / s;
    float acc = 0.f;
#pragma unroll
    for (int j = 0; j < NSEG; ++j) acc += (l[j] * inv) * v[j * SEGLEN + p];
    out[o] = acc;
}

extern "C" void kernel_launch(void* const* d_in, const int* in_sizes, int n_in,
                              void* d_out, int out_size, void* d_ws, size_t ws_size,
                              hipStream_t stream) {
    const float* q = (const float*)d_in[0];   // queries [1,32,8,32] f32
    const float* k = (const float*)d_in[1];   // keys
    const float* v = (const float*)d_in[2];   // values
    float* out = (float*)d_out;               // [8192] f32
    float* dists = (float*)d_ws;              // 64 floats scratch

    dtw_sk4_kernel<<<dim3(NSEG * NSEG), dim3(256), 0, stream>>>(q, k, dists);
    softmax_out_kernel<<<dim3((NSEG * SEGLEN + 255) / 256), dim3(256), 0, stream>>>(v, dists, out);
}